// Round 1
// baseline (442.314 us; speedup 1.0000x reference)
//
#include <hip/hip_runtime.h>
#include <hip/hip_bf16.h>
#include <stdint.h>

// Problem constants (reference: N=16384, F=1024, B=512)
#define N_ROWS 16384
#define F_DIM  1024
#define B_DIM  512
#define K_DIM  1536   // F + B
#define G_DIM  4096   // 4*F

typedef __bf16 v8bf __attribute__((ext_vector_type(8)));
typedef float  v4f  __attribute__((ext_vector_type(4)));

typedef const void __attribute__((address_space(1)))* gptr1;
typedef void       __attribute__((address_space(3)))* lptr3;

__device__ __forceinline__ unsigned short f2bf(float x) {
    union { float f; unsigned int u; } c; c.f = x;
    unsigned int u = c.u;
    return (unsigned short)((u + 0x7FFFu + ((u >> 16) & 1u)) >> 16);  // RNE; inputs finite
}

// ---------------------------------------------------------------------------
// Pack A = bf16([h_prev | behavior]) row-major (N_ROWS x K_DIM).
// grid = N_ROWS blocks, 192 threads (each thread converts 8 elements).
// ---------------------------------------------------------------------------
__global__ void pack_x(const float* __restrict__ behavior,
                       const float* __restrict__ h_prev,
                       unsigned short* __restrict__ A) {
    const int row = blockIdx.x;
    const int col = threadIdx.x * 8;              // 0..1528, never straddles 1024
    const float* src = (col < F_DIM)
        ? h_prev   + (long)row * F_DIM + col
        : behavior + (long)row * B_DIM + (col - F_DIM);
    float4 lo = *(const float4*)src;
    float4 hi = *(const float4*)(src + 4);
    union { unsigned short u[8]; int4 v; } p;
    p.u[0] = f2bf(lo.x); p.u[1] = f2bf(lo.y); p.u[2] = f2bf(lo.z); p.u[3] = f2bf(lo.w);
    p.u[4] = f2bf(hi.x); p.u[5] = f2bf(hi.y); p.u[6] = f2bf(hi.z); p.u[7] = f2bf(hi.w);
    *(int4*)(A + (long)row * K_DIM + col) = p.v;
}

// ---------------------------------------------------------------------------
// Pack W' = bf16 gate-interleaved [Wh | Wx]: row g' = 4*f + gate maps to
// original row g = gate*F + f.  Also permuted bias b'[g'] = b[g].
// grid = G_DIM blocks, 192 threads.
// ---------------------------------------------------------------------------
__global__ void pack_w(const float* __restrict__ Wh,
                       const float* __restrict__ Wx,
                       const float* __restrict__ b,
                       unsigned short* __restrict__ W,
                       float* __restrict__ bperm) {
    const int gp   = blockIdx.x;
    const int gate = gp & 3;
    const int f    = gp >> 2;
    const int g    = gate * F_DIM + f;
    const int col  = threadIdx.x * 8;
    const float* src = (col < F_DIM)
        ? Wh + (long)g * F_DIM + col
        : Wx + (long)g * B_DIM + (col - F_DIM);
    float4 lo = *(const float4*)src;
    float4 hi = *(const float4*)(src + 4);
    union { unsigned short u[8]; int4 v; } p;
    p.u[0] = f2bf(lo.x); p.u[1] = f2bf(lo.y); p.u[2] = f2bf(lo.z); p.u[3] = f2bf(lo.w);
    p.u[4] = f2bf(hi.x); p.u[5] = f2bf(hi.y); p.u[6] = f2bf(hi.z); p.u[7] = f2bf(hi.w);
    *(int4*)(W + (long)gp * K_DIM + col) = p.v;
    if (threadIdx.x == 0) bperm[gp] = b[g];
}

__device__ __forceinline__ float sigmoidf_fast(float x) {
    return 1.f / (1.f + __expf(-x));
}
__device__ __forceinline__ float tanhf_fast(float x) {
    // 1 - 2/(e^{2x}+1): exp overflow -> +1, underflow -> -1 (both correct)
    return 1.f - 2.f / (__expf(2.f * x) + 1.f);
}

// ---------------------------------------------------------------------------
// Fused GEMM (gates = A @ W'^T) + bias + activations + c/h epilogue.
// 128x128 output tile per block (rows x interleaved-gate cols = 32 f values),
// 4 waves in 2x2, each wave 64x64 via 4x4 grid of 16x16x32 bf16 MFMAs, BK=64,
// global_load_lds width-16 staging.  m97 structure (874 TF @ 4k^3).
// ---------------------------------------------------------------------------
__global__ __launch_bounds__(256, 2) void lstm_gemm(
    const unsigned short* __restrict__ A,   // [N_ROWS][K_DIM] bf16
    const unsigned short* __restrict__ W,   // [G_DIM][K_DIM]  bf16, interleaved
    const float* __restrict__ bperm,        // [G_DIM]
    const float* __restrict__ c_prev,       // [N_ROWS][F_DIM]
    float* __restrict__ out)                // [N_ROWS][F_DIM]
{
    __shared__ unsigned short lds[16384];   // 32 KB: A tile [0,8192), W tile [8192,16384)

    const int m0   = blockIdx.y * 128;
    const int n0   = blockIdx.x * 128;
    const int tid  = threadIdx.x;
    const int lane = tid & 63;
    const int wave = tid >> 6;
    const int wm   = (wave >> 1) * 64;      // wave row offset in tile
    const int wn   = (wave & 1) * 64;       // wave col offset in tile
    const int lrow = lane & 15;
    const int quad = lane >> 4;

    v4f acc[4][4] = {};                     // 64 fp32 accum / lane

    // Staging: each wave stages 32 rows of A and 32 rows of W per K-step.
    // One global_load_lds call = 64 lanes x 16 B = 8 rows x 64 bf16.
    const int ls_row = lane >> 3;           // 0..7 row within 8-row chunk
    const int ls_col = (lane & 7) * 8;      // bf16 col within row
    const unsigned short* a_g = A + (long)(m0 + wave * 32 + ls_row) * K_DIM + ls_col;
    const unsigned short* w_g = W + (long)(n0 + wave * 32 + ls_row) * K_DIM + ls_col;
    unsigned short* a_l = &lds[(wave * 32) * 64];
    unsigned short* w_l = &lds[8192 + (wave * 32) * 64];

    for (int k0 = 0; k0 < K_DIM; k0 += 64) {
#pragma unroll
        for (int c = 0; c < 4; ++c) {
            __builtin_amdgcn_global_load_lds((gptr1)(a_g + (long)c * 8 * K_DIM + k0),
                                             (lptr3)(a_l + c * 8 * 64), 16, 0, 0);
            __builtin_amdgcn_global_load_lds((gptr1)(w_g + (long)c * 8 * K_DIM + k0),
                                             (lptr3)(w_l + c * 8 * 64), 16, 0, 0);
        }
        __syncthreads();   // compiler emits vmcnt(0) drain before s_barrier

#pragma unroll
        for (int kk = 0; kk < 64; kk += 32) {
            v8bf af[4], bf[4];
#pragma unroll
            for (int mt = 0; mt < 4; ++mt)
                af[mt] = *(const v8bf*)&lds[(wm + mt * 16 + lrow) * 64 + kk + quad * 8];
#pragma unroll
            for (int nt = 0; nt < 4; ++nt)
                bf[nt] = *(const v8bf*)&lds[8192 + (wn + nt * 16 + lrow) * 64 + kk + quad * 8];
#pragma unroll
            for (int mt = 0; mt < 4; ++mt)
#pragma unroll
                for (int nt = 0; nt < 4; ++nt)
                    acc[mt][nt] = __builtin_amdgcn_mfma_f32_16x16x32_bf16(
                        af[mt], bf[nt], acc[mt][nt], 0, 0, 0);
        }
        __syncthreads();
    }

    // ---- fused epilogue ----
    // C/D layout: col = lane&15, row = quad*4 + reg.  Interleaved col = 4*f+gate,
    // so lanes {base..base+3} (base = lane&~3) hold gates i,f,g,o of f-group.
    // 4x4 shfl_xor transpose: lane ends with all 4 gates of row quad*4+(lane&3).
    const int l3 = lane & 3;
    const int fl = (lane & 15) >> 2;
#pragma unroll
    for (int nt = 0; nt < 4; ++nt) {
        const int   gcol = n0 + wn + nt * 16 + lrow;
        const float bias = bperm[gcol];
#pragma unroll
        for (int mt = 0; mt < 4; ++mt) {
            float a0 = acc[mt][nt][0] + bias;
            float a1 = acc[mt][nt][1] + bias;
            float a2 = acc[mt][nt][2] + bias;
            float a3 = acc[mt][nt][3] + bias;
            // stage 1: xor 1, reg bit 0
            float s0 = (lane & 1) ? a0 : a1;
            float s1 = (lane & 1) ? a2 : a3;
            float r0 = __shfl_xor(s0, 1, 64);
            float r1 = __shfl_xor(s1, 1, 64);
            if (lane & 1) { a0 = r0; a2 = r1; } else { a1 = r0; a3 = r1; }
            // stage 2: xor 2, reg bit 1
            s0 = (lane & 2) ? a0 : a2;
            s1 = (lane & 2) ? a1 : a3;
            r0 = __shfl_xor(s0, 2, 64);
            r1 = __shfl_xor(s1, 2, 64);
            if (lane & 2) { a0 = r0; a1 = r1; } else { a2 = r0; a3 = r1; }
            // a0..a3 = pre-activation i,f,g,o for (row = quad*4+l3, f-group fl)
            const float iv = sigmoidf_fast(a0);
            const float fv = sigmoidf_fast(a1);
            const float gv = tanhf_fast(a2);
            const float ov = sigmoidf_fast(a3);
            const int grow = m0 + wm + mt * 16 + quad * 4 + l3;
            const int gf   = ((n0 + wn + nt * 16) >> 2) + fl;
            const float cp = c_prev[(long)grow * F_DIM + gf];
            const float cv = fv * cp + iv * gv;
            const float hv = ov * tanhf_fast(cv);
            out[(long)grow * F_DIM + gf] = hv;
        }
    }
}

// ---------------------------------------------------------------------------
// Inputs (setup_inputs order): behavior, h_prev, c_prev, Wh, Wx, b  (all fp32)
// Output: h (N_ROWS x F_DIM fp32)
// Workspace: A bf16 48 MB | W' bf16 12 MB | b' 16 KB  (total ~63 MB)
// ---------------------------------------------------------------------------
extern "C" void kernel_launch(void* const* d_in, const int* in_sizes, int n_in,
                              void* d_out, int out_size, void* d_ws, size_t ws_size,
                              hipStream_t stream) {
    const float* behavior = (const float*)d_in[0];
    const float* h_prev   = (const float*)d_in[1];
    const float* c_prev   = (const float*)d_in[2];
    const float* Wh       = (const float*)d_in[3];
    const float* Wx       = (const float*)d_in[4];
    const float* b        = (const float*)d_in[5];
    float* out = (float*)d_out;

    unsigned short* A  = (unsigned short*)d_ws;
    unsigned short* W  = A + (size_t)N_ROWS * K_DIM;
    float*       bperm = (float*)(W + (size_t)G_DIM * K_DIM);

    pack_x<<<N_ROWS, 192, 0, stream>>>(behavior, h_prev, A);
    pack_w<<<G_DIM, 192, 0, stream>>>(Wh, Wx, b, W, bperm);
    lstm_gemm<<<dim3(G_DIM / 128, N_ROWS / 128), 256, 0, stream>>>(A, W, bperm, c_prev, out);
}

// Round 2
// 405.067 us; speedup vs baseline: 1.0920x; 1.0920x over previous
//
#include <hip/hip_runtime.h>
#include <hip/hip_bf16.h>
#include <stdint.h>

// Problem constants (reference: N=16384, F=1024, B=512)
#define N_ROWS 16384
#define F_DIM  1024
#define B_DIM  512
#define K_DIM  1536   // F + B
#define G_DIM  4096   // 4*F
#define CB_STR 36     // padded fp32 stride for epilogue LDS tile (bank-conflict-free)

typedef __bf16 v8bf __attribute__((ext_vector_type(8)));
typedef float  v4f  __attribute__((ext_vector_type(4)));

typedef const void __attribute__((address_space(1)))* gptr1;
typedef void       __attribute__((address_space(3)))* lptr3;

__device__ __forceinline__ unsigned short f2bf(float x) {
    union { float f; unsigned int u; } c; c.f = x;
    unsigned int u = c.u;
    return (unsigned short)((u + 0x7FFFu + ((u >> 16) & 1u)) >> 16);  // RNE; inputs finite
}

// ---------------------------------------------------------------------------
// Pack A = bf16([h_prev | behavior]) row-major (N_ROWS x K_DIM).
// ---------------------------------------------------------------------------
__global__ void pack_x(const float* __restrict__ behavior,
                       const float* __restrict__ h_prev,
                       unsigned short* __restrict__ A) {
    const int row = blockIdx.x;
    const int col = threadIdx.x * 8;              // 0..1528, never straddles 1024
    const float* src = (col < F_DIM)
        ? h_prev   + (long)row * F_DIM + col
        : behavior + (long)row * B_DIM + (col - F_DIM);
    float4 lo = *(const float4*)src;
    float4 hi = *(const float4*)(src + 4);
    union { unsigned short u[8]; int4 v; } p;
    p.u[0] = f2bf(lo.x); p.u[1] = f2bf(lo.y); p.u[2] = f2bf(lo.z); p.u[3] = f2bf(lo.w);
    p.u[4] = f2bf(hi.x); p.u[5] = f2bf(hi.y); p.u[6] = f2bf(hi.z); p.u[7] = f2bf(hi.w);
    *(int4*)(A + (long)row * K_DIM + col) = p.v;
}

// ---------------------------------------------------------------------------
// Pack W' = bf16 gate-interleaved [Wh | Wx]: row g' = 4*f + gate maps to
// original row g = gate*F + f.  Also permuted bias b'[g'] = b[g].
// ---------------------------------------------------------------------------
__global__ void pack_w(const float* __restrict__ Wh,
                       const float* __restrict__ Wx,
                       const float* __restrict__ b,
                       unsigned short* __restrict__ W,
                       float* __restrict__ bperm) {
    const int gp   = blockIdx.x;
    const int gate = gp & 3;
    const int f    = gp >> 2;
    const int g    = gate * F_DIM + f;
    const int col  = threadIdx.x * 8;
    const float* src = (col < F_DIM)
        ? Wh + (long)g * F_DIM + col
        : Wx + (long)g * B_DIM + (col - F_DIM);
    float4 lo = *(const float4*)src;
    float4 hi = *(const float4*)(src + 4);
    union { unsigned short u[8]; int4 v; } p;
    p.u[0] = f2bf(lo.x); p.u[1] = f2bf(lo.y); p.u[2] = f2bf(lo.z); p.u[3] = f2bf(lo.w);
    p.u[4] = f2bf(hi.x); p.u[5] = f2bf(hi.y); p.u[6] = f2bf(hi.z); p.u[7] = f2bf(hi.w);
    *(int4*)(W + (long)gp * K_DIM + col) = p.v;
    if (threadIdx.x == 0) bperm[gp] = b[g];
}

__device__ __forceinline__ float sigmoidf_fast(float x) {
    return 1.f / (1.f + __expf(-x));
}
__device__ __forceinline__ float tanhf_fast(float x) {
    return 1.f - 2.f / (__expf(2.f * x) + 1.f);   // saturates correctly at +/-1
}

// ---------------------------------------------------------------------------
// Fused GEMM (gates = A @ W'^T) + bias + activations + c/h epilogue.
// 128x128 tile, 4 waves 2x2, wave = 4x4 grid of 16x16x32 bf16 MFMA, BK=64.
// XOR-swizzled LDS: slot s of row r holds global col-block s ^ (r&7), so
// fragment ds_read_b128 spreads 8 lanes on each of the 8 16B-slots ->
// even 8-phase bank schedule (b128 floor), zero excess conflict.
// Epilogue: c_prev/h round-trip through padded LDS tile for coalesced
// 128B-per-row global traffic (kills the 2.3x write amplification).
// ---------------------------------------------------------------------------
__global__ __launch_bounds__(256, 2) void lstm_gemm(
    const unsigned short* __restrict__ A,   // [N_ROWS][K_DIM] bf16
    const unsigned short* __restrict__ W,   // [G_DIM][K_DIM]  bf16, interleaved
    const float* __restrict__ bperm,        // [G_DIM]
    const float* __restrict__ c_prev,       // [N_ROWS][F_DIM]
    float* __restrict__ out)                // [N_ROWS][F_DIM]
{
    __shared__ unsigned short lds[16384];   // 32 KB: A tile [0,8192), W tile [8192,16384)

    const int m0   = blockIdx.y * 128;
    const int n0   = blockIdx.x * 128;
    const int tid  = threadIdx.x;
    const int lane = tid & 63;
    const int wave = tid >> 6;
    const int wm   = (wave >> 1) * 64;      // wave row offset in tile
    const int wn   = (wave & 1) * 64;       // wave col offset in tile
    const int lrow = lane & 15;
    const int quad = lane >> 4;
    const int r7   = lrow & 7;              // row low bits for read-side swizzle

    v4f acc[4][4] = {};                     // 64 fp32 accum / lane

    // Staging with XOR swizzle: lane l writes LDS slot (l&7) of row (l>>3);
    // we point its global fetch at col-block (l&7) ^ (l>>3).
    const int ls_row = lane >> 3;                 // 0..7
    const int ls_blk = (lane & 7) ^ ls_row;       // global 8-elem block index
    const unsigned short* a_g = A + (long)(m0 + wave * 32 + ls_row) * K_DIM + ls_blk * 8;
    const unsigned short* w_g = W + (long)(n0 + wave * 32 + ls_row) * K_DIM + ls_blk * 8;
    unsigned short* a_l = &lds[(wave * 32) * 64];
    unsigned short* w_l = &lds[8192 + (wave * 32) * 64];

    for (int k0 = 0; k0 < K_DIM; k0 += 64) {
#pragma unroll
        for (int c = 0; c < 4; ++c) {
            __builtin_amdgcn_global_load_lds((gptr1)(a_g + (long)c * 8 * K_DIM + k0),
                                             (lptr3)(a_l + c * 8 * 64), 16, 0, 0);
            __builtin_amdgcn_global_load_lds((gptr1)(w_g + (long)c * 8 * K_DIM + k0),
                                             (lptr3)(w_l + c * 8 * 64), 16, 0, 0);
        }
        __syncthreads();

#pragma unroll
        for (int kk = 0; kk < 64; kk += 32) {
            const int ko = kk >> 3;                       // 0 or 4
            const int sa = (((quad + ko) ^ r7) * 8);      // swizzled slot offset (bf16)
            v8bf af[4], bf[4];
#pragma unroll
            for (int mt = 0; mt < 4; ++mt)
                af[mt] = *(const v8bf*)&lds[(wm + mt * 16 + lrow) * 64 + sa];
#pragma unroll
            for (int nt = 0; nt < 4; ++nt)
                bf[nt] = *(const v8bf*)&lds[8192 + (wn + nt * 16 + lrow) * 64 + sa];
#pragma unroll
            for (int mt = 0; mt < 4; ++mt)
#pragma unroll
                for (int nt = 0; nt < 4; ++nt)
                    acc[mt][nt] = __builtin_amdgcn_mfma_f32_16x16x32_bf16(
                        af[mt], bf[nt], acc[mt][nt], 0, 0, 0);
        }
        __syncthreads();
    }

    // ---- stage c_prev tile (128 rows x 32 f-cols) into padded LDS, coalesced ----
    float* cbuf = (float*)lds;                    // [128][CB_STR] = 18 KB (< 32 KB)
    const int fbase = n0 >> 2;
#pragma unroll
    for (int i = 0; i < 4; ++i) {
        const int q  = i * 256 + tid;             // 0..1023 float4-chunks
        const int r  = q >> 3;
        const int c4 = (q & 7) * 4;
        *(float4*)&cbuf[r * CB_STR + c4] =
            *(const float4*)&c_prev[(long)(m0 + r) * F_DIM + fbase + c4];
    }
    __syncthreads();

    // ---- fused epilogue (in-register 4x4 gate transpose, LDS-staged c/h) ----
    const int l3 = lane & 3;
    const int fl = (lane & 15) >> 2;
#pragma unroll
    for (int nt = 0; nt < 4; ++nt) {
        const int   gcol = n0 + wn + nt * 16 + lrow;
        const float bias = bperm[gcol];
#pragma unroll
        for (int mt = 0; mt < 4; ++mt) {
            float a0 = acc[mt][nt][0] + bias;
            float a1 = acc[mt][nt][1] + bias;
            float a2 = acc[mt][nt][2] + bias;
            float a3 = acc[mt][nt][3] + bias;
            // 4x4 transpose across lane quads: stage 1 (xor 1, reg bit 0)
            float s0 = (lane & 1) ? a0 : a1;
            float s1 = (lane & 1) ? a2 : a3;
            float r0 = __shfl_xor(s0, 1, 64);
            float r1 = __shfl_xor(s1, 1, 64);
            if (lane & 1) { a0 = r0; a2 = r1; } else { a1 = r0; a3 = r1; }
            // stage 2 (xor 2, reg bit 1)
            s0 = (lane & 2) ? a0 : a2;
            s1 = (lane & 2) ? a1 : a3;
            r0 = __shfl_xor(s0, 2, 64);
            r1 = __shfl_xor(s1, 2, 64);
            if (lane & 2) { a0 = r0; a1 = r1; } else { a2 = r0; a3 = r1; }
            // a0..a3 = pre-activation i,f,g,o for (local row, local f-col)
            const float iv = sigmoidf_fast(a0);
            const float fv = sigmoidf_fast(a1);
            const float gv = tanhf_fast(a2);
            const float ov = sigmoidf_fast(a3);
            const int lr = wm + mt * 16 + quad * 4 + l3;       // 0..127
            const int lc = ((wn + nt * 16) >> 2) + fl;         // 0..31
            const float cp = cbuf[lr * CB_STR + lc];
            const float cv = fv * cp + iv * gv;
            cbuf[lr * CB_STR + lc] = ov * tanhf_fast(cv);      // same-lane cell, no race
        }
    }
    __syncthreads();

    // ---- coalesced h store: 128B contiguous per row ----
#pragma unroll
    for (int i = 0; i < 4; ++i) {
        const int q  = i * 256 + tid;
        const int r  = q >> 3;
        const int c4 = (q & 7) * 4;
        *(float4*)&out[(long)(m0 + r) * F_DIM + fbase + c4] =
            *(const float4*)&cbuf[r * CB_STR + c4];
    }
}

// ---------------------------------------------------------------------------
// Inputs (setup_inputs order): behavior, h_prev, c_prev, Wh, Wx, b  (all fp32)
// Output: h (N_ROWS x F_DIM fp32)
// Workspace: A bf16 48 MB | W' bf16 12 MB | b' 16 KB
// ---------------------------------------------------------------------------
extern "C" void kernel_launch(void* const* d_in, const int* in_sizes, int n_in,
                              void* d_out, int out_size, void* d_ws, size_t ws_size,
                              hipStream_t stream) {
    const float* behavior = (const float*)d_in[0];
    const float* h_prev   = (const float*)d_in[1];
    const float* c_prev   = (const float*)d_in[2];
    const float* Wh       = (const float*)d_in[3];
    const float* Wx       = (const float*)d_in[4];
    const float* b        = (const float*)d_in[5];
    float* out = (float*)d_out;

    unsigned short* A  = (unsigned short*)d_ws;
    unsigned short* W  = A + (size_t)N_ROWS * K_DIM;
    float*       bperm = (float*)(W + (size_t)G_DIM * K_DIM);

    pack_x<<<N_ROWS, 192, 0, stream>>>(behavior, h_prev, A);
    pack_w<<<G_DIM, 192, 0, stream>>>(Wh, Wx, b, W, bperm);
    lstm_gemm<<<dim3(G_DIM / 128, N_ROWS / 128), 256, 0, stream>>>(A, W, bperm, c_prev, out);
}